// Round 7
// baseline (727.456 us; speedup 1.0000x reference)
//
#include <hip/hip_runtime.h>
#include <stdint.h>

#define TSTEPS 1000
#define NB 256
#define NF 64
#define NH 256   // H1 == H2 == 256
#define CHUNK 8
#define NCH 125  // 125 * 8 == 1000, no tail

// Prep: transpose W2 (H2,H1) -> W2T[h1][h2] in d_ws for coalesced gathers,
// and zero the two global spike counters.
__global__ void snn_prep(const float* __restrict__ W2, float* __restrict__ W2T,
                         unsigned int* __restrict__ counts) {
    int idx = blockIdx.x * 256 + threadIdx.x;     // idx = h1*256 + h2
    W2T[idx] = W2[(idx & 255) * 256 + (idx >> 8)];
    if (idx < 2) counts[idx] = 0u;
}

// Load one float4 of W1 into 4 named scalars.
#define LDQ(i, wa, wb, wc, wd) \
    { float4 t_ = W1v[i]; wa = t_.x; wb = t_.y; wc = t_.z; wd = t_.w; }
// Anchor 4 values as asm-defs: not rematerializable as loads, so they must
// stay live in VGPRs (budget 256 via waves_per_eu(2,2); ~130 live -> no spill).
#define PIN4(a, b, c, d) asm("" : "+v"(a), "+v"(b), "+v"(c), "+v"(d));

// Masked accumulate of 4 features (ascending f), +0.0f identity for inactive
// features -> bit-exact same order as the original sparse ctz gather.
#define MAQ(acc, fb, wa, wb, wc, wd) \
    acc += ((xm >> (fb)) & 1ull) ? (wa) : 0.f; \
    acc += ((xm >> ((fb) + 1)) & 1ull) ? (wb) : 0.f; \
    acc += ((xm >> ((fb) + 2)) & 1ull) ? (wc) : 0.f; \
    acc += ((xm >> ((fb) + 3)) & 1ull) ? (wd) : 0.f;

// Producer step: ballot (x from registers), 4 chains of 16 features, mem1
// update, spk1 publish. ZERO memory operations — pure VALU/SALU/LDS-write.
#define PSTEP(pb, tt, xv) do {                                                \
    unsigned long long xm = __ballot((xv) > 0.f);                             \
    float a0 = 0.f, a1 = 0.f, a2 = 0.f, a3 = 0.f;                             \
    MAQ(a0, 0,  w00, w01, w02, w03) MAQ(a0, 4,  w04, w05, w06, w07)           \
    MAQ(a0, 8,  w08, w09, w10, w11) MAQ(a0, 12, w12, w13, w14, w15)           \
    MAQ(a1, 16, w16, w17, w18, w19) MAQ(a1, 20, w20, w21, w22, w23)           \
    MAQ(a1, 24, w24, w25, w26, w27) MAQ(a1, 28, w28, w29, w30, w31)           \
    MAQ(a2, 32, w32, w33, w34, w35) MAQ(a2, 36, w36, w37, w38, w39)           \
    MAQ(a2, 40, w40, w41, w42, w43) MAQ(a2, 44, w44, w45, w46, w47)           \
    MAQ(a3, 48, w48, w49, w50, w51) MAQ(a3, 52, w52, w53, w54, w55)           \
    MAQ(a3, 56, w56, w57, w58, w59) MAQ(a3, 60, w60, w61, w62, w63)           \
    float cur1 = b1h + ((a0 + a1) + (a2 + a3));                               \
    float reset1 = (mem1 > 1.f) ? 1.f : 0.f;                                  \
    mem1 = 0.8187307530779818f * mem1 + cur1 - reset1; /* beta1=exp(-1/5) */  \
    bool s1 = (mem1 - 1.f) > 0.f;                                             \
    cnt1 += (int)s1;                                                          \
    unsigned long long sm = __ballot(s1);                                     \
    if (lane == 0) scnt8[pb][(tt) * 4 + wv] = (unsigned char)__popcll(sm);    \
    if (s1) {                                                                 \
        int rank = __popcll(sm & ((1ull << lane) - 1ull));                    \
        slist[pb][tt][(wv << 6) + rank] = (unsigned char)h;                   \
    }                                                                         \
} while (0)

// Consumer step: read the 5 metadata words (named locals), branch-free
// first-4 gather with value masking (order matches the guarded loop
// exactly), rare overflow path, mem2 update.
#define CSTEP(cb, tt) do {                                                    \
    unsigned int cwv = *(const unsigned int*)&scnt8[cb][(tt) * 4];            \
    unsigned int u0 = *(const unsigned int*)&slist[cb][tt][0];                \
    unsigned int u1 = *(const unsigned int*)&slist[cb][tt][64];               \
    unsigned int u2 = *(const unsigned int*)&slist[cb][tt][128];              \
    unsigned int u3 = *(const unsigned int*)&slist[cb][tt][192];              \
    int c0 = (int)(cwv & 255u),        c1 = (int)((cwv >> 8) & 255u);         \
    int c2 = (int)((cwv >> 16) & 255u), c3 = (int)((cwv >> 24) & 255u);       \
    float q0 = 0.f, q1 = 0.f, q2 = 0.f, q3 = 0.f;                             \
    _Pragma("unroll")                                                         \
    for (int i = 0; i < 4; ++i) {                                             \
        float v0 = W2Th[(int)((u0 >> (8 * i)) & 255u) << 8];                  \
        float v1 = W2Th[(int)((u1 >> (8 * i)) & 255u) << 8];                  \
        float v2 = W2Th[(int)((u2 >> (8 * i)) & 255u) << 8];                  \
        float v3 = W2Th[(int)((u3 >> (8 * i)) & 255u) << 8];                  \
        q0 += (i < c0) ? v0 : 0.f;                                            \
        q1 += (i < c1) ? v1 : 0.f;                                            \
        q2 += (i < c2) ? v2 : 0.f;                                            \
        q3 += (i < c3) ? v3 : 0.f;                                            \
    }                                                                         \
    int nmax = max(max(c0, c1), max(c2, c3));                                 \
    if (nmax > 4) {   /* rare overflow path (per-wave spike count > 4) */     \
        const unsigned char* sl = &slist[cb][tt][0];                          \
        for (int i = 4; i < nmax; ++i) {                                      \
            if (i < c0) q0 += W2Th[(int)sl[i] << 8];                          \
            if (i < c1) q1 += W2Th[(int)sl[64 + i] << 8];                     \
            if (i < c2) q2 += W2Th[(int)sl[128 + i] << 8];                    \
            if (i < c3) q3 += W2Th[(int)sl[192 + i] << 8];                    \
        }                                                                     \
    }                                                                         \
    float cur2 = b2h + ((q0 + q1) + (q2 + q3));                               \
    float reset2 = (mem2 > 1.f) ? 1.f : 0.f;                                  \
    mem2 = 0.9048374180359595f * mem2 + cur2 - reset2; /* beta2=exp(-1/10) */ \
    bool s2 = (mem2 - 1.f) > 0.f;                                             \
    cnt2 += (int)s2;                                                          \
    mem2s += mem2;                                                            \
} while (0)

// Main: one 512-thread workgroup per batch, wave-specialized pipeline.
//   waves 0-3 (producer): own mem1[h], layer 1 for chunk c -> slist[c&1].
//   waves 4-7 (consumer): own mem2[h], layer 2 for chunk c-1.
// Wave i and wave i+4 share a SIMD, so the producer's pure-VALU step stream
// fills the consumer's L2-gather latency. waves_per_eu(2,2) sets a hard
// 256-VGPR budget; PIN4 asm-defs make the W1 values non-rematerializable,
// so they finally stay register-resident (rounds 1-6: VGPR 68-88 proved the
// scheduler kept sinking the W1 loads back into the loop).
__attribute__((amdgpu_flat_work_group_size(512, 512), amdgpu_waves_per_eu(2, 2)))
__global__ void snn_main(const float* __restrict__ spikes,
                         const float* __restrict__ W1,
                         const float* __restrict__ b1,
                         const float* __restrict__ W2T,
                         const float* __restrict__ b2,
                         const float* __restrict__ Wr,
                         const float* __restrict__ br,
                         float* __restrict__ out,
                         unsigned int* __restrict__ counts) {
    const int b = blockIdx.x;
    const int tid = threadIdx.x;
    const int lane = tid & 63;
    const int wv = tid >> 6;          // 0..7
    const bool producer = (wv < 4);
    const int h = tid & 255;          // hidden index within the role group

    __shared__ unsigned char slist[2][CHUNK][256]; // per-chunk-buf spk1 lists
    __shared__ unsigned char scnt8[2][CHUNK * 4];  // per-step per-wave counts
    __shared__ float rp0[4], rp1[4];
    __shared__ int rc1[4], rc2[4];

    const size_t xstride = (size_t)NB * NF;
    const float* xbase = spikes + (size_t)b * NF + lane;  // per-lane x ptr
    const float* W2Th = W2T + h;

    // W1 row h as 64 NAMED float registers.
    float w00 = 0.f, w01 = 0.f, w02 = 0.f, w03 = 0.f, w04 = 0.f, w05 = 0.f;
    float w06 = 0.f, w07 = 0.f, w08 = 0.f, w09 = 0.f, w10 = 0.f, w11 = 0.f;
    float w12 = 0.f, w13 = 0.f, w14 = 0.f, w15 = 0.f, w16 = 0.f, w17 = 0.f;
    float w18 = 0.f, w19 = 0.f, w20 = 0.f, w21 = 0.f, w22 = 0.f, w23 = 0.f;
    float w24 = 0.f, w25 = 0.f, w26 = 0.f, w27 = 0.f, w28 = 0.f, w29 = 0.f;
    float w30 = 0.f, w31 = 0.f, w32 = 0.f, w33 = 0.f, w34 = 0.f, w35 = 0.f;
    float w36 = 0.f, w37 = 0.f, w38 = 0.f, w39 = 0.f, w40 = 0.f, w41 = 0.f;
    float w42 = 0.f, w43 = 0.f, w44 = 0.f, w45 = 0.f, w46 = 0.f, w47 = 0.f;
    float w48 = 0.f, w49 = 0.f, w50 = 0.f, w51 = 0.f, w52 = 0.f, w53 = 0.f;
    float w54 = 0.f, w55 = 0.f, w56 = 0.f, w57 = 0.f, w58 = 0.f, w59 = 0.f;
    float w60 = 0.f, w61 = 0.f, w62 = 0.f, w63 = 0.f;

    float mem1 = 0.f, mem2 = 0.f, mem2s = 0.f;
    int cnt1 = 0, cnt2 = 0;
    float b1h = 0.f, b2h = 0.f;
    float xq0 = 0.f, xq1 = 0.f, xq2 = 0.f, xq3 = 0.f;
    float xq4 = 0.f, xq5 = 0.f, xq6 = 0.f, xq7 = 0.f;

    if (producer) {
        const float4* W1v = (const float4*)(W1 + h * NF);
        LDQ(0,  w00, w01, w02, w03) LDQ(1,  w04, w05, w06, w07)
        LDQ(2,  w08, w09, w10, w11) LDQ(3,  w12, w13, w14, w15)
        LDQ(4,  w16, w17, w18, w19) LDQ(5,  w20, w21, w22, w23)
        LDQ(6,  w24, w25, w26, w27) LDQ(7,  w28, w29, w30, w31)
        LDQ(8,  w32, w33, w34, w35) LDQ(9,  w36, w37, w38, w39)
        LDQ(10, w40, w41, w42, w43) LDQ(11, w44, w45, w46, w47)
        LDQ(12, w48, w49, w50, w51) LDQ(13, w52, w53, w54, w55)
        LDQ(14, w56, w57, w58, w59) LDQ(15, w60, w61, w62, w63)
        PIN4(w00, w01, w02, w03) PIN4(w04, w05, w06, w07)
        PIN4(w08, w09, w10, w11) PIN4(w12, w13, w14, w15)
        PIN4(w16, w17, w18, w19) PIN4(w20, w21, w22, w23)
        PIN4(w24, w25, w26, w27) PIN4(w28, w29, w30, w31)
        PIN4(w32, w33, w34, w35) PIN4(w36, w37, w38, w39)
        PIN4(w40, w41, w42, w43) PIN4(w44, w45, w46, w47)
        PIN4(w48, w49, w50, w51) PIN4(w52, w53, w54, w55)
        PIN4(w56, w57, w58, w59) PIN4(w60, w61, w62, w63)
        b1h = b1[h];
        // chunk-0 inputs: per-lane x[t][b][lane]; 64 lanes -> 256B coalesced
        xq0 = xbase[0];
        xq1 = xbase[xstride];
        xq2 = xbase[2 * xstride];
        xq3 = xbase[3 * xstride];
        xq4 = xbase[4 * xstride];
        xq5 = xbase[5 * xstride];
        xq6 = xbase[6 * xstride];
        xq7 = xbase[7 * xstride];
    } else {
        b2h = b2[h];
    }

    for (int c = 0; c < NCH; ++c) {
        if (producer) {
            const int pb = c & 1;
            // ---- layer 1: CHUNK steps, zero memory ops ----
            PSTEP(pb, 0, xq0); PSTEP(pb, 1, xq1);
            PSTEP(pb, 2, xq2); PSTEP(pb, 3, xq3);
            PSTEP(pb, 4, xq4); PSTEP(pb, 5, xq5);
            PSTEP(pb, 6, xq6); PSTEP(pb, 7, xq7);
            // prefetch next chunk's inputs; consumed after barrier +
            // consumer overlap -> latency hidden.
            int cn = (c + 1 < NCH) ? c + 1 : 0;  // clamped dummy on last
            const float* xb = xbase + (size_t)cn * CHUNK * xstride;
            xq0 = xb[0];
            xq1 = xb[xstride];
            xq2 = xb[2 * xstride];
            xq3 = xb[3 * xstride];
            xq4 = xb[4 * xstride];
            xq5 = xb[5 * xstride];
            xq6 = xb[6 * xstride];
            xq7 = xb[7 * xstride];
        } else if (c > 0) {
            const int cb = (c - 1) & 1;
            // ---- layer 2: CHUNK steps for chunk c-1 ----
            CSTEP(cb, 0); CSTEP(cb, 1); CSTEP(cb, 2); CSTEP(cb, 3);
            CSTEP(cb, 4); CSTEP(cb, 5); CSTEP(cb, 6); CSTEP(cb, 7);
        }
        __syncthreads();   // chunk handoff: slist[pb] ready; buffers swap
    }
    // pipeline epilogue: last chunk's layer 2
    if (!producer) {
        const int cb = (NCH - 1) & 1;
        CSTEP(cb, 0); CSTEP(cb, 1); CSTEP(cb, 2); CSTEP(cb, 3);
        CSTEP(cb, 4); CSTEP(cb, 5); CSTEP(cb, 6); CSTEP(cb, 7);
    }

    // readout: out[b,:] = (mem2_sum/T) @ Wr.T + br ; role-local reductions
    if (producer) {
        int rcs1 = cnt1;
        for (int off = 32; off > 0; off >>= 1) rcs1 += __shfl_down(rcs1, off);
        if (lane == 0) rc1[wv] = rcs1;
    } else {
        float v = mem2s / 1000.0f;
        float p0 = v * Wr[h];
        float p1 = v * Wr[NH + h];
        int rcs2 = cnt2;
        for (int off = 32; off > 0; off >>= 1) {
            p0 += __shfl_down(p0, off);
            p1 += __shfl_down(p1, off);
            rcs2 += __shfl_down(rcs2, off);
        }
        if (lane == 0) { rp0[wv - 4] = p0; rp1[wv - 4] = p1; rc2[wv - 4] = rcs2; }
    }
    __syncthreads();
    if (tid == 0) {
        out[2 * b]     = ((rp0[0] + rp0[1]) + (rp0[2] + rp0[3])) + br[0];
        out[2 * b + 1] = ((rp1[0] + rp1[1]) + (rp1[2] + rp1[3])) + br[1];
        atomicAdd(&counts[0], (unsigned)(rc1[0] + rc1[1] + rc1[2] + rc1[3]));
        atomicAdd(&counts[1], (unsigned)(rc2[0] + rc2[1] + rc2[2] + rc2[3]));
    }
}

__global__ void snn_finalize(const unsigned int* __restrict__ counts,
                             float* __restrict__ out) {
    if (threadIdx.x < 2)
        out[512 + threadIdx.x] = (float)counts[threadIdx.x] / 65536000.0f; // T*B*256
}

extern "C" void kernel_launch(void* const* d_in, const int* in_sizes, int n_in,
                              void* d_out, int out_size, void* d_ws, size_t ws_size,
                              hipStream_t stream) {
    const float* spikes = (const float*)d_in[0];
    const float* W1     = (const float*)d_in[1];
    const float* b1     = (const float*)d_in[2];
    const float* W2     = (const float*)d_in[3];
    const float* b2     = (const float*)d_in[4];
    const float* Wr     = (const float*)d_in[5];
    const float* br     = (const float*)d_in[6];
    float* out = (float*)d_out;

    float* W2T = (float*)d_ws;                                   // 256 KB
    unsigned int* counts = (unsigned int*)((char*)d_ws + (size_t)NH * NH * sizeof(float));

    snn_prep<<<256, 256, 0, stream>>>(W2, W2T, counts);
    snn_main<<<256, 512, 0, stream>>>(spikes, W1, b1, W2T, b2, Wr, br, out, counts);
    snn_finalize<<<1, 64, 0, stream>>>(counts, out);
}